// Round 3
// baseline (97.384 us; speedup 1.0000x reference)
//
#include <hip/hip_runtime.h>

// GlobalAttentionModule collapses algebraically:
//   weight = softmax(score, axis=-1)  =>  sum_j weight[b,c,i,j] == 1
//   out = (v[:,:,:,None] * weight).sum(-1) = v
// where v = relu(GroupNorm32(Wv @ feat + bv, gn_v_g, gn_v_b)).
// Only inputs 0 (feat), 5 (Wv), 6 (bv), 7 (gn_v_g), 8 (gn_v_b) matter.
// All tensors are float32 storage (bf16-quantized values).
//
// dur_us is dominated by harness reset (268 MB ws poison ~39.5 us/iter);
// this round maximizes per-block TLP (1024 thr = 4 waves/SIMD) to shave the
// only controllable component: the kernel's L2-latency-bound inner loop.

#define BATCH  2
#define CH     128
#define NPOS   512
#define GROUPS 32
#define CPG    4            // channels per group = 128/32
#define GEPS   1e-5f

// One block per (batch, group): 4 channels x 512 positions = 2048 elements
// (exactly the GroupNorm reduction span). 1024 threads: thread t owns channel
// j = t>>8 and positions 2p, 2p+1 where p = t&255 (2 fp32 accumulators).
__global__ __launch_bounds__(1024) void vpath_kernel(
    const float* __restrict__ feat,   // [B, C, N]
    const float* __restrict__ Wv,     // [C, C]  (out_ch, in_ch)
    const float* __restrict__ bv,     // [C]
    const float* __restrict__ gam,    // [C]
    const float* __restrict__ bet,    // [C]
    float* __restrict__ out)          // [B, C, N]
{
    const int b   = blockIdx.x >> 5;
    const int g   = blockIdx.x & 31;
    const int ch0 = g * CPG;
    const int t   = threadIdx.x;      // 0..1023
    const int j   = t >> 8;           // 0..3  channel within group
    const int p   = t & 255;          // position pair index

    __shared__ float w[CPG][CH];      // 2 KB: Wv rows for this group's channels
    __shared__ float red[16], red2[16];
    __shared__ float stats[2];        // mean, rsqrt(var+eps)

    // Stage Wv rows for channels ch0..ch0+3 into LDS (512 floats).
    if (t < CPG * CH) {
        int jj = t >> 7;              // 0..3
        int cc = t & 127;
        w[jj][cc] = Wv[(ch0 + jj) * CH + cc];
    }
    __syncthreads();

    // v[b, ch0+j, 2p+e] = sum_c Wv[ch0+j, c] * feat[b, c, 2p+e]
    float acc0 = 0.f, acc1 = 0.f;
    const float2* fp =
        reinterpret_cast<const float2*>(feat + (size_t)b * CH * NPOS) + p;
    #pragma unroll 8
    for (int c = 0; c < CH; ++c) {
        float2 f = fp[c * (NPOS / 2)];        // coalesced 8B/lane
        float wv = w[j][c];                   // LDS broadcast within wave
        acc0 = fmaf(wv, f.x, acc0);
        acc1 = fmaf(wv, f.y, acc1);
    }

    // Bias, then per-thread partial stats.
    const float bias = bv[ch0 + j];
    acc0 += bias;
    acc1 += bias;
    float s  = acc0 + acc1;
    float s2 = acc0 * acc0 + acc1 * acc1;

    // Wave (64-lane) shuffle reduction, then cross-wave via LDS (16 waves).
    #pragma unroll
    for (int off = 32; off > 0; off >>= 1) {
        s  += __shfl_down(s, off);
        s2 += __shfl_down(s2, off);
    }
    const int wave = t >> 6;
    if ((t & 63) == 0) {
        red[wave]  = s;
        red2[wave] = s2;
    }
    __syncthreads();
    if (t < 16) {
        float a = red[t], a2 = red2[t];
        #pragma unroll
        for (int off = 8; off > 0; off >>= 1) {
            a  += __shfl_down(a, off);
            a2 += __shfl_down(a2, off);
        }
        if (t == 0) {
            const float inv_n = 1.0f / (float)(CPG * NPOS);   // 1/2048
            float m   = a * inv_n;
            float var = a2 * inv_n - m * m;
            stats[0] = m;
            stats[1] = rsqrtf(var + GEPS);
        }
    }
    __syncthreads();
    const float m = stats[0];
    const float r = stats[1];

    // Normalize + affine + ReLU, store float2 (coalesced 8B/lane).
    const float ga = gam[ch0 + j];
    const float be = bet[ch0 + j];
    float2 y;
    y.x = fmaxf((acc0 - m) * r * ga + be, 0.0f);
    y.y = fmaxf((acc1 - m) * r * ga + be, 0.0f);
    reinterpret_cast<float2*>(out + (size_t)(b * CH + ch0 + j) * NPOS)[p] = y;
}

extern "C" void kernel_launch(void* const* d_in, const int* in_sizes, int n_in,
                              void* d_out, int out_size, void* d_ws, size_t ws_size,
                              hipStream_t stream) {
    const float* feat = (const float*)d_in[0];   // [2,128,512]
    const float* Wv   = (const float*)d_in[5];   // [128,128]
    const float* bv   = (const float*)d_in[6];   // [128]
    const float* gng  = (const float*)d_in[7];   // [128]
    const float* gnb  = (const float*)d_in[8];   // [128]
    float* out = (float*)d_out;                  // [2,128,512]

    vpath_kernel<<<dim3(BATCH * GROUPS), dim3(1024), 0, stream>>>(
        feat, Wv, bv, gng, gnb, out);
}